// Round 4
// baseline (120.100 us; speedup 1.0000x reference)
//
#include <hip/hip_runtime.h>
#include <hip/hip_bf16.h>

#define NN 1024
#define LN_EPS 1e-5f

typedef __bf16 bf16x8 __attribute__((ext_vector_type(8)));
typedef float floatx4 __attribute__((ext_vector_type(4)));
typedef float floatx2 __attribute__((ext_vector_type(2)));

__device__ __forceinline__ floatx4 splat4(float s) { return (floatx4){s, s, s, s}; }

// Kernel 1 (blocks 0..255, 4 nodes/block): per-node precompute.
//   Ap[i][h] = emb[i]·W1[:64,h] + b1[h]   (f32 row-major)
//   Bt4      = emb[j]·W1[64:,h]           (f32, float4-interleaved: [(h>>2)][j][h&3])
//   sumA/sumB: per-node sums (LN1 mean is linear)
// Block 256: wave0 packs W2^T into MFMA A-frag order; wave1 = w2colsum
// (Wc[k] = Σ_h' W2[k][h'], for the linear Σpre2 trick); wave2 = Σb2.
__global__ __launch_bounds__(256) void precompute_ab(
    const float* __restrict__ emb, const float* __restrict__ W1,
    const float* __restrict__ b1, const float* __restrict__ W2, const float* __restrict__ b2,
    float* __restrict__ Ap, float* __restrict__ Bt4,
    float* __restrict__ sumA, float* __restrict__ sumB,
    float* __restrict__ Wc, float* __restrict__ sb2, __bf16* __restrict__ Wf) {
    int tid = threadIdx.x, wv = tid >> 6, lane = tid & 63;
    if (blockIdx.x == 256) {
        if (wv == 0) {
            // A-frag for mfma_f32_16x16x32_bf16: lane l holds A[m][k], m=l&15, k=(l>>4)*8+t.
            int m_l = lane & 15, kg = lane >> 4;
#pragma unroll
            for (int mt = 0; mt < 4; mt++)
#pragma unroll
                for (int kc = 0; kc < 2; kc++) {
                    bf16x8 f;
#pragma unroll
                    for (int t = 0; t < 8; t++) {
                        int k = kc * 32 + kg * 8 + t;
                        f[t] = (__bf16)W2[k * 64 + mt * 16 + m_l];
                    }
                    *(bf16x8*)&Wf[((mt * 2 + kc) * 64 + lane) * 8] = f;
                }
        } else if (wv == 1) {
            float s = 0.f;
#pragma unroll
            for (int h = 0; h < 64; h++) s += W2[lane * 64 + h];
            Wc[lane] = s;
        } else if (wv == 2) {
            float v = b2[lane];
#pragma unroll
            for (int off = 1; off < 64; off <<= 1) v += __shfl_xor(v, off);
            if (lane == 0) sb2[0] = v;
        }
        return;
    }
    __shared__ __align__(16) float e[4][64];
    int i = blockIdx.x * 4 + wv, h = lane;
    e[wv][h] = emb[i * 64 + h];
    __syncthreads();
    float a = b1[h], b = 0.f;
#pragma unroll
    for (int d = 0; d < 64; d++) {
        a = fmaf(e[wv][d], W1[d * 64 + h], a);
        b = fmaf(e[wv][d], W1[(64 + d) * 64 + h], b);
    }
    Ap[i * 64 + h] = a;
    Bt4[(h >> 2) * 4096 + i * 4 + (h & 3)] = b;
    float ra = a, rb = b;
#pragma unroll
    for (int off = 1; off < 64; off <<= 1) {
        ra += __shfl_xor(ra, off);
        rb += __shfl_xor(rb, off);
    }
    if (h == 0) { sumA[i] = ra; sumB[i] = rb; }
}

// Kernel 2: fused pair-MLP. Block=256 (4 waves). Block b: i=b>>2, wave w covers
// j in [(b&3)*256 + w*64, +64). Lane = pair within the wave tile.
// Stage-1 x kept in regs/AGPRs (round-2 dataflow: no serial MFMA on the critical
// path). During LN1 we also accumulate s2p = h1[p]·Wc + Σb2 = Σ_h' pre2[h',p]
// (linearity), delivered to the epilogue via one shfl per tile.
__global__ __launch_bounds__(256, 4) void fused(
    const float* __restrict__ Ap, const float* __restrict__ Bt4, const __bf16* __restrict__ Wf,
    const float* __restrict__ sumA, const float* __restrict__ sumB,
    const float* __restrict__ Wcp, const float* __restrict__ sb2p,
    const float* __restrict__ g1, const float* __restrict__ be1, const float* __restrict__ b2,
    const float* __restrict__ g2, const float* __restrict__ be2, const float* __restrict__ W3,
    const float* __restrict__ b3, const float* __restrict__ mask, float* __restrict__ out) {
    __shared__ __align__(16) float Arow[64], G1[64], BE1[64], B2s[64], G2s[64], BE2s[64],
        W3s[64], WCs[64];
    __shared__ __align__(16) __bf16 h1t[4][64 * 64];  // per-wave 8KB bf16 h1 tile, XOR-swizzled

    int tid = threadIdx.x;
    int wave = tid >> 6, lane = tid & 63;
    int i = blockIdx.x >> 2;
    int j0 = (blockIdx.x & 3) * 256 + wave * 64;

    if (tid < 64) {
        Arow[tid] = Ap[i * 64 + tid];
        G1[tid] = g1[tid];  BE1[tid] = be1[tid];
        B2s[tid] = b2[tid]; G2s[tid] = g2[tid]; BE2s[tid] = be2[tid];
        W3s[tid] = W3[tid]; WCs[tid] = Wcp[tid];
    }
    __syncthreads();

    int m_l = lane & 15, kg = lane >> 4;

    // ---- Stage 1: x = A'[i] + B[:,j], Σx² on the fly (Σx precomputed) ----
    float sBj = sumB[j0 + lane];
    const float* btp = Bt4 + (j0 + lane) * 4;
    floatx4 xs[16];
    floatx4 qA = splat4(0.f), qB = splat4(0.f);
#pragma unroll
    for (int g = 0; g < 16; g++) {
        floatx4 bb = *(const floatx4*)(btp + g * 4096);
        floatx4 aa = *(const floatx4*)&Arow[g * 4];
        floatx4 v = aa + bb;
        xs[g] = v;
        if (g & 1) qB += v * v;
        else       qA += v * v;
    }
    floatx4 qs = qA + qB;
    float sq = (qs[0] + qs[1]) + (qs[2] + qs[3]);
    float m1 = (sumA[i] + sBj) * 0.015625f;
    float rs1 = rsqrtf(fmaf(m1, -m1, sq * 0.015625f) + LN_EPS);
    floatx4 RS = splat4(rs1), OF = splat4(-m1 * rs1);

    // ---- LN1 + ReLU -> bf16 LDS row (XOR-swizzled), fused s2p dot with Wc ----
    __bf16* rowp = &h1t[wave][lane * 64];
    int sw = lane & 7;
    floatx4 s2acc = splat4(0.f);
#pragma unroll
    for (int c = 0; c < 8; c++) {
        floatx4 gg0 = *(const floatx4*)&G1[c * 8];
        floatx4 gg1 = *(const floatx4*)&G1[c * 8 + 4];
        floatx4 ee0 = *(const floatx4*)&BE1[c * 8];
        floatx4 ee1 = *(const floatx4*)&BE1[c * 8 + 4];
        floatx4 y0 = (xs[2 * c] * RS + OF) * gg0 + ee0;
        floatx4 y1 = (xs[2 * c + 1] * RS + OF) * gg1 + ee1;
        y0 = __builtin_elementwise_max(y0, splat4(0.f));
        y1 = __builtin_elementwise_max(y1, splat4(0.f));
        s2acc = y0 * (*(const floatx4*)&WCs[c * 8]) + s2acc;
        s2acc = y1 * (*(const floatx4*)&WCs[c * 8 + 4]) + s2acc;
        bf16x8 fr;
        fr[0] = (__bf16)y0[0]; fr[1] = (__bf16)y0[1]; fr[2] = (__bf16)y0[2]; fr[3] = (__bf16)y0[3];
        fr[4] = (__bf16)y1[0]; fr[5] = (__bf16)y1[1]; fr[6] = (__bf16)y1[2]; fr[7] = (__bf16)y1[3];
        *(bf16x8*)(rowp + ((c ^ sw) * 8)) = fr;
    }
    float s2p = ((s2acc[0] + s2acc[1]) + (s2acc[2] + s2acc[3])) + sb2p[0];

    // W2^T fragments (coalesced, prepacked) — issue while LDS writes drain
    bf16x8 afrag[4][2];
#pragma unroll
    for (int mt = 0; mt < 4; mt++)
#pragma unroll
        for (int kc = 0; kc < 2; kc++)
            afrag[mt][kc] = *(const bf16x8*)&Wf[((mt * 2 + kc) * 64 + lane) * 8];

    // wave-private tile: drain DS before cross-lane reads
    asm volatile("s_waitcnt lgkmcnt(0)" ::: "memory");

    // ---- MFMA: pre2^T = W2^T @ h1^T, accumulator initialized with b2 ----
    floatx4 b2r[4];
#pragma unroll
    for (int mt = 0; mt < 4; mt++) b2r[mt] = *(const floatx4*)&B2s[mt * 16 + kg * 4];
    floatx4 acc[4][4];
#pragma unroll
    for (int mt = 0; mt < 4; mt++)
#pragma unroll
        for (int nt = 0; nt < 4; nt++) acc[mt][nt] = b2r[mt];

    const __bf16* wbase = &h1t[wave][0];
#pragma unroll
    for (int nt = 0; nt < 4; nt++) {
        int pair = nt * 16 + m_l;
#pragma unroll
        for (int kc = 0; kc < 2; kc++) {
            int chunk = kc * 4 + kg;
            bf16x8 bfrag = *(const bf16x8*)(wbase + pair * 64 + ((chunk ^ (pair & 7)) * 8));
#pragma unroll
            for (int mt = 0; mt < 4; mt++)
                acc[mt][nt] =
                    __builtin_amdgcn_mfma_f32_16x16x32_bf16(afrag[mt][kc], bfrag, acc[mt][nt], 0, 0, 0);
        }
    }

    // ---- Epilogue params hoisted to regs (afrag dead now) ----
    floatx4 g2r[4], e2r[4], w3r[4];
#pragma unroll
    for (int mt = 0; mt < 4; mt++) {
        g2r[mt] = *(const floatx4*)&G2s[mt * 16 + kg * 4];
        e2r[mt] = *(const floatx4*)&BE2s[mt * 16 + kg * 4];
        w3r[mt] = *(const floatx4*)&W3s[mt * 16 + kg * 4];
    }
    float b3v = b3[0];

    // ---- LN2 + ReLU + W3 dot + mask. Lane holds h'=mt*16+kg*4+r, pair=nt*16+m_l ----
#pragma unroll
    for (int nt = 0; nt < 4; nt++) {
        float s2 = __shfl(s2p, nt * 16 + m_l);   // Σ(pre2+b2) for this lane's pair
        floatx2 q2v = {0.f, 0.f};
#pragma unroll
        for (int mt = 0; mt < 4; mt++) {
            floatx2 vlo = {acc[mt][nt][0], acc[mt][nt][1]};
            floatx2 vhi = {acc[mt][nt][2], acc[mt][nt][3]};
            q2v += vlo * vlo;
            q2v += vhi * vhi;
        }
        float q2 = q2v[0] + q2v[1];
        q2 += __shfl_xor(q2, 16); q2 += __shfl_xor(q2, 32);
        float m2 = s2 * 0.015625f;
        float rs2 = rsqrtf(fmaf(m2, -m2, q2 * 0.015625f) + LN_EPS);
        floatx2 P2 = {rs2, rs2};
        float o2s = -m2 * rs2;
        floatx2 O2 = {o2s, o2s};

        floatx2 scv = {0.f, 0.f};
#pragma unroll
        for (int mt = 0; mt < 4; mt++) {
#pragma unroll
            for (int hh = 0; hh < 2; hh++) {
                floatx2 v = {acc[mt][nt][2 * hh], acc[mt][nt][2 * hh + 1]};
                floatx2 g = {g2r[mt][2 * hh], g2r[mt][2 * hh + 1]};
                floatx2 e = {e2r[mt][2 * hh], e2r[mt][2 * hh + 1]};
                floatx2 w = {w3r[mt][2 * hh], w3r[mt][2 * hh + 1]};
                floatx2 y = (v * P2 + O2) * g + e;
                y = __builtin_elementwise_max(y, (floatx2){0.f, 0.f});
                scv += y * w;
            }
        }
        float sc = scv[0] + scv[1];
        sc += __shfl_xor(sc, 16); sc += __shfl_xor(sc, 32);

        if (kg == 0) {
            int j = j0 + nt * 16 + m_l;
            int p = i * NN + j;
            out[p] = (i == j) ? 0.f : (sc + b3v) * mask[p];
        }
    }
}

extern "C" void kernel_launch(void* const* d_in, const int* in_sizes, int n_in,
                              void* d_out, int out_size, void* d_ws, size_t ws_size,
                              hipStream_t stream) {
    const float* emb = (const float*)d_in[0];
    const float* mask = (const float*)d_in[1];
    const float* W1 = (const float*)d_in[2];
    const float* b1 = (const float*)d_in[3];
    const float* g1 = (const float*)d_in[4];
    const float* be1 = (const float*)d_in[5];
    const float* W2 = (const float*)d_in[6];
    const float* b2 = (const float*)d_in[7];
    const float* g2 = (const float*)d_in[8];
    const float* be2 = (const float*)d_in[9];
    const float* W3 = (const float*)d_in[10];
    const float* b3 = (const float*)d_in[11];
    float* out = (float*)d_out;

    float* Ap = (float*)d_ws;                 // 256 KB
    float* Bt4 = Ap + 65536;                  // 256 KB (float4-interleaved B)
    float* sA = Bt4 + 65536;                  // 4 KB
    float* sB = sA + 1024;                    // 4 KB
    float* Wc = sB + 1024;                    // 256 B
    float* sb2 = Wc + 64;                     // 4 B (+pad)
    __bf16* Wf = (__bf16*)(sb2 + 64);         // 8 KB

    precompute_ab<<<257, 256, 0, stream>>>(emb, W1, b1, W2, b2, Ap, Bt4, sA, sB, Wc, sb2, Wf);
    fused<<<4096, 256, 0, stream>>>(Ap, Bt4, Wf, sA, sB, Wc, sb2,
                                    g1, be1, b2, g2, be2, W3, b3, mask, out);
}

// Round 5
// 114.550 us; speedup vs baseline: 1.0485x; 1.0485x over previous
//
#include <hip/hip_runtime.h>
#include <hip/hip_bf16.h>

#define NN 1024
#define LN_EPS 1e-5f

typedef __bf16 bf16x8 __attribute__((ext_vector_type(8)));
typedef float floatx4 __attribute__((ext_vector_type(4)));
typedef float floatx2 __attribute__((ext_vector_type(2)));

// Kernel 1 (blocks 0..1023): per-node precompute.
//   Ap[i][h] = emb[i]·W1[:64,h] + b1[h]   (f32 row-major)
//   Bt[h][j] = emb[j]·W1[64:,h]           (f32 transposed [64][1024])
//   sumA/sumB: per-node sums (LN1 mean is linear)
// Block 1024: pack W2^T into MFMA A-frag order (bf16).
__global__ void precompute_ab(const float* __restrict__ emb, const float* __restrict__ W1,
                              const float* __restrict__ b1, const float* __restrict__ W2,
                              float* __restrict__ Ap, float* __restrict__ Bt,
                              float* __restrict__ sumA, float* __restrict__ sumB,
                              __bf16* __restrict__ Wf) {
    if (blockIdx.x == 1024) {
        // A-frag for mfma_f32_16x16x32_bf16: lane l holds A[m][k], m=l&15, k=(l>>4)*8+t.
        int lane = threadIdx.x;
        int m_l = lane & 15, kg = lane >> 4;
#pragma unroll
        for (int mt = 0; mt < 4; mt++)
#pragma unroll
            for (int kc = 0; kc < 2; kc++) {
                bf16x8 f;
#pragma unroll
                for (int t = 0; t < 8; t++) {
                    int k = kc * 32 + kg * 8 + t;
                    f[t] = (__bf16)W2[k * 64 + mt * 16 + m_l];
                }
                *(bf16x8*)&Wf[((mt * 2 + kc) * 64 + lane) * 8] = f;
            }
        return;
    }
    __shared__ __align__(16) float e[64];
    int i = blockIdx.x, h = threadIdx.x;
    e[h] = emb[i * 64 + h];
    __syncthreads();
    float a = b1[h], b = 0.f;
#pragma unroll
    for (int d = 0; d < 64; d++) {
        a = fmaf(e[d], W1[d * 64 + h], a);
        b = fmaf(e[d], W1[(64 + d) * 64 + h], b);
    }
    Ap[i * 64 + h] = a;
    Bt[h * NN + i] = b;
    float ra = a, rb = b;
#pragma unroll
    for (int off = 1; off < 64; off <<= 1) {
        ra += __shfl_xor(ra, off);
        rb += __shfl_xor(rb, off);
    }
    if (h == 0) { sumA[i] = ra; sumB[i] = rb; }
}

// Kernel 2: fused pair-MLP — round-2 dataflow (best measured memory pattern),
// with: LDS = h1 tile ONLY (32768 B exactly -> 5 blocks/CU LDS cap), zero
// __syncthreads (params via scalar/global loads; h1t is wave-private),
// b2-in-accumulator init, hoisted epilogue params.
// Block=256 (4 waves). Block b: i=b>>2, wave w covers j in [(b&3)*256+w*64, +64).
__global__ __launch_bounds__(256, 4) void fused(
    const float* __restrict__ Ap, const float* __restrict__ Bt, const __bf16* __restrict__ Wf,
    const float* __restrict__ sumA, const float* __restrict__ sumB,
    const float* __restrict__ g1, const float* __restrict__ be1, const float* __restrict__ b2,
    const float* __restrict__ g2, const float* __restrict__ be2, const float* __restrict__ W3,
    const float* __restrict__ b3, const float* __restrict__ mask, float* __restrict__ out) {
    __shared__ __align__(16) __bf16 h1t[4][64 * 64];  // 32768 B exactly; per-wave 8KB, XOR-swizzled

    int tid = threadIdx.x;
    int wave = tid >> 6, lane = tid & 63;
    int i = blockIdx.x >> 2;
    int j0 = (blockIdx.x & 3) * 256 + wave * 64;

    int m_l = lane & 15, kg = lane >> 4;
    const float* Arow = Ap + i * 64;   // uniform address -> scalar loads

    // ---- Stage 1: x = A'[i] + Bt[:,j], Σx² on the fly (Σx precomputed) ----
    float sBj = sumB[j0 + lane];
    const float* btp = Bt + j0 + lane;
    floatx2 x2[32];
    floatx2 qa = {0.f, 0.f}, qb = {0.f, 0.f};
#pragma unroll
    for (int h2 = 0; h2 < 32; h2++) {
        floatx2 bb = { btp[(2 * h2) * NN], btp[(2 * h2 + 1) * NN] };
        floatx2 aa = *(const floatx2*)&Arow[2 * h2];
        floatx2 v = aa + bb;
        x2[h2] = v;
        if (h2 & 1) qb += v * v;
        else        qa += v * v;
    }
    floatx2 qs = qa + qb;
    float sq = qs[0] + qs[1];
    float m1 = (sumA[i] + sBj) * 0.015625f;
    float rs1 = rsqrtf(fmaf(m1, -m1, sq * 0.015625f) + LN_EPS);
    floatx2 p1 = {rs1, rs1};
    float ofs = -m1 * rs1;
    floatx2 o1 = {ofs, ofs};

    // W2^T fragments, coalesced from prepacked buffer
    bf16x8 afrag[4][2];
#pragma unroll
    for (int mt = 0; mt < 4; mt++)
#pragma unroll
        for (int kc = 0; kc < 2; kc++)
            afrag[mt][kc] = *(const bf16x8*)&Wf[((mt * 2 + kc) * 64 + lane) * 8];

    // ---- LN1 + ReLU -> bf16, write own row to LDS (chunk XOR-swizzle) ----
    __bf16* rowp = &h1t[wave][lane * 64];
    int sw = lane & 7;
#pragma unroll
    for (int c = 0; c < 8; c++) {
        bf16x8 fr;
#pragma unroll
        for (int t = 0; t < 4; t++) {
            floatx2 gg = *(const floatx2*)&g1[c * 8 + 2 * t];   // uniform -> scalar load
            floatx2 ee = *(const floatx2*)&be1[c * 8 + 2 * t];  // uniform -> scalar load
            floatx2 xn = x2[c * 4 + t] * p1 + o1;
            floatx2 y  = xn * gg + ee;
            y = __builtin_elementwise_max(y, (floatx2){0.f, 0.f});
            fr[2 * t]     = (__bf16)y[0];
            fr[2 * t + 1] = (__bf16)y[1];
        }
        *(bf16x8*)(rowp + ((c ^ sw) * 8)) = fr;
    }
    // wave-private tile: drain DS before cross-lane reads (no block barrier needed)
    asm volatile("s_waitcnt lgkmcnt(0)" ::: "memory");

    // ---- MFMA: pre2^T = W2^T @ h1^T, accumulator initialized with b2 ----
    floatx4 b2r[4];
#pragma unroll
    for (int mt = 0; mt < 4; mt++) b2r[mt] = *(const floatx4*)&b2[mt * 16 + kg * 4];
    floatx4 acc[4][4];
#pragma unroll
    for (int mt = 0; mt < 4; mt++)
#pragma unroll
        for (int nt = 0; nt < 4; nt++) acc[mt][nt] = b2r[mt];

    const __bf16* wbase = &h1t[wave][0];
#pragma unroll
    for (int nt = 0; nt < 4; nt++) {
        int pair = nt * 16 + m_l;
#pragma unroll
        for (int kc = 0; kc < 2; kc++) {
            int chunk = kc * 4 + kg;
            bf16x8 bfrag = *(const bf16x8*)(wbase + pair * 64 + ((chunk ^ (pair & 7)) * 8));
#pragma unroll
            for (int mt = 0; mt < 4; mt++)
                acc[mt][nt] =
                    __builtin_amdgcn_mfma_f32_16x16x32_bf16(afrag[mt][kc], bfrag, acc[mt][nt], 0, 0, 0);
        }
    }

    // ---- Epilogue params hoisted to regs (afrag dead now); lane-varying -> vector loads
    floatx4 g2r[4], e2r[4], w3r[4];
#pragma unroll
    for (int mt = 0; mt < 4; mt++) {
        g2r[mt] = *(const floatx4*)&g2[mt * 16 + kg * 4];
        e2r[mt] = *(const floatx4*)&be2[mt * 16 + kg * 4];
        w3r[mt] = *(const floatx4*)&W3[mt * 16 + kg * 4];
    }
    float b3v = b3[0];

    // ---- LN2 + ReLU + W3 dot + mask. Lane holds h'=mt*16+kg*4+r, pair=nt*16+m_l ----
#pragma unroll
    for (int nt = 0; nt < 4; nt++) {
        floatx2 s2v = {0.f, 0.f}, q2v = {0.f, 0.f};
#pragma unroll
        for (int mt = 0; mt < 4; mt++) {
            floatx2 vlo = {acc[mt][nt][0], acc[mt][nt][1]};
            floatx2 vhi = {acc[mt][nt][2], acc[mt][nt][3]};
            s2v += vlo; s2v += vhi;
            q2v += vlo * vlo; q2v += vhi * vhi;
        }
        float s2 = s2v[0] + s2v[1];
        float q2 = q2v[0] + q2v[1];
        s2 += __shfl_xor(s2, 16); s2 += __shfl_xor(s2, 32);
        q2 += __shfl_xor(q2, 16); q2 += __shfl_xor(q2, 32);
        float m2 = s2 * 0.015625f;
        float rs2 = rsqrtf(fmaf(m2, -m2, q2 * 0.015625f) + LN_EPS);
        floatx2 P2 = {rs2, rs2};
        float o2s = -m2 * rs2;
        floatx2 O2 = {o2s, o2s};

        floatx2 scv = {0.f, 0.f};
#pragma unroll
        for (int mt = 0; mt < 4; mt++) {
#pragma unroll
            for (int hh = 0; hh < 2; hh++) {
                floatx2 v = {acc[mt][nt][2 * hh], acc[mt][nt][2 * hh + 1]};
                floatx2 g = {g2r[mt][2 * hh], g2r[mt][2 * hh + 1]};
                floatx2 e = {e2r[mt][2 * hh], e2r[mt][2 * hh + 1]};
                floatx2 w = {w3r[mt][2 * hh], w3r[mt][2 * hh + 1]};
                floatx2 y = (v * P2 + O2) * g + e;
                y = __builtin_elementwise_max(y, (floatx2){0.f, 0.f});
                scv += y * w;
            }
        }
        float sc = scv[0] + scv[1];
        sc += __shfl_xor(sc, 16); sc += __shfl_xor(sc, 32);

        if (kg == 0) {
            int j = j0 + nt * 16 + m_l;
            int p = i * NN + j;
            out[p] = (i == j) ? 0.f : (sc + b3v) * mask[p];
        }
    }
}

extern "C" void kernel_launch(void* const* d_in, const int* in_sizes, int n_in,
                              void* d_out, int out_size, void* d_ws, size_t ws_size,
                              hipStream_t stream) {
    const float* emb = (const float*)d_in[0];
    const float* mask = (const float*)d_in[1];
    const float* W1 = (const float*)d_in[2];
    const float* b1 = (const float*)d_in[3];
    const float* g1 = (const float*)d_in[4];
    const float* be1 = (const float*)d_in[5];
    const float* W2 = (const float*)d_in[6];
    const float* b2 = (const float*)d_in[7];
    const float* g2 = (const float*)d_in[8];
    const float* be2 = (const float*)d_in[9];
    const float* W3 = (const float*)d_in[10];
    const float* b3 = (const float*)d_in[11];
    float* out = (float*)d_out;

    float* Ap = (float*)d_ws;                 // 256 KB
    float* Bt = Ap + 65536;                   // 256 KB
    float* sA = Bt + 65536;                   // 4 KB
    float* sB = sA + 1024;                    // 4 KB
    __bf16* Wf = (__bf16*)(sB + 1024);        // 8 KB

    precompute_ab<<<1025, 64, 0, stream>>>(emb, W1, b1, W2, Ap, Bt, sA, sB, Wf);
    fused<<<4096, 256, 0, stream>>>(Ap, Bt, Wf, sA, sB,
                                    g1, be1, b2, g2, be2, W3, b3, mask, out);
}